// Round 2
// baseline (1221.094 us; speedup 1.0000x reference)
//
#include <hip/hip_runtime.h>

// Superpixel mean pooling:
//   x: [B=4, C=128, H=512, W=512] f32, labels: [B, 1, H, W] int32 (values < 512)
//   out: [B, L=512, C=128] f32 = mean of x over pixels sharing a label.
//
// Plan: LDS-accumulated scatter-add. Block = (batch, 32-channel group,
// 8192-pixel slice); 64 KB LDS acc[32][512]; coalesced float4 streaming of x;
// LDS atomicAdd per pixel; global atomicAdd flush; separate count histogram;
// final divide.
//
// R1 bug fix: 256 threads = 4 waves (wave=64!), so each wave owns 8 channels
// (4 waves x 8 = 32), not 4. Previous version left channels 16..31 zero.

constexpr int Bn = 4, Cn = 128, Hn = 512, Wn = 512;
constexpr int Pn = Hn * Wn;        // 262144 pixels per image
constexpr int Ln = 512;            // labels
constexpr int CPB = 32;            // channels per block
constexpr int CG = Cn / CPB;       // 4 channel groups
constexpr int SPLITS = 32;         // pixel splits per (b, cg)
constexpr int NPIX = Pn / SPLITS;  // 8192 pixels per block
constexpr int CPW = 8;             // channels per wave (4 waves * 8 = 32)

__global__ void zero_kernel(float4* __restrict__ out4, int* __restrict__ counts) {
    const int i = blockIdx.x * 256 + threadIdx.x;   // 65536 threads
    out4[i] = float4{0.f, 0.f, 0.f, 0.f};
    if (i < Bn * Ln) counts[i] = 0;
}

// 16 blocks per batch, each histograms 16384 pixels in LDS then flushes.
__global__ void count_kernel(const int* __restrict__ labels, int* __restrict__ counts) {
    __shared__ int cnt[Ln];
    const int b   = blockIdx.x >> 4;
    const int blk = blockIdx.x & 15;
    for (int i = threadIdx.x; i < Ln; i += 256) cnt[i] = 0;
    __syncthreads();
    const int4* lab4 = (const int4*)(labels + b * Pn + blk * (Pn / 16));
#pragma unroll
    for (int it = 0; it < (Pn / 16) / (4 * 256); ++it) {   // 16 iters
        int4 l = lab4[it * 256 + threadIdx.x];
        atomicAdd(&cnt[l.x], 1);
        atomicAdd(&cnt[l.y], 1);
        atomicAdd(&cnt[l.z], 1);
        atomicAdd(&cnt[l.w], 1);
    }
    __syncthreads();
    for (int i = threadIdx.x; i < Ln; i += 256)
        atomicAdd(&counts[b * Ln + i], cnt[i]);
}

__global__ void __launch_bounds__(256, 2)
sum_kernel(const float* __restrict__ x, const int* __restrict__ labels,
           float* __restrict__ out) {
    // acc[c_local][label] — 32*512*4 = 64 KB (2 blocks/CU of the 160 KB pool).
    // Bank for (c,l) = l%32: random labels -> near-random banks in the hot loop.
    __shared__ float acc[CPB * Ln];

    const int bid = blockIdx.x;
    const int ps  = bid & (SPLITS - 1);
    const int cg  = (bid >> 5) & (CG - 1);
    const int b   = bid >> 7;

    for (int i = threadIdx.x; i < CPB * Ln; i += 256) acc[i] = 0.f;
    __syncthreads();

    const int wave = threadIdx.x >> 6;   // 4 waves per block
    const int lane = threadIdx.x & 63;
    const int p0   = ps * NPIX;

    const int4* lab4 = (const int4*)(labels + b * Pn + p0);
    const float4* xp[CPW];
    float* accl[CPW];
#pragma unroll
    for (int j = 0; j < CPW; ++j) {
        const int c_local = wave * CPW + j;        // 4 waves x 8 = 32 channels
        xp[j]   = (const float4*)(x + (size_t)(b * Cn + cg * CPB + c_local) * Pn + p0);
        accl[j] = acc + c_local * Ln;
    }

    for (int it = 0; it < NPIX / (64 * 4); ++it) {  // 32 iters; each wave walks all 8192 px
        const int idx = it * 64 + lane;             // coalesced float4/int4
        const int4 l = lab4[idx];
#pragma unroll
        for (int j = 0; j < CPW; ++j) {
            const float4 v = xp[j][idx];
            atomicAdd(&accl[j][l.x], v.x);
            atomicAdd(&accl[j][l.y], v.y);
            atomicAdd(&accl[j][l.z], v.z);
            atomicAdd(&accl[j][l.w], v.w);
        }
    }
    __syncthreads();

    // Flush: i -> (l = i>>5, c_local = i&31) so global atomics are 32
    // consecutive floats per l (coalesced). LDS read has 32-way bank alias
    // (stride 512) but flush is ~1% of kernel time.
    for (int i = threadIdx.x; i < CPB * Ln; i += 256) {
        const int l = i >> 5;
        const int c_local = i & 31;
        atomicAdd(&out[((size_t)b * Ln + l) * Cn + cg * CPB + c_local],
                  acc[c_local * Ln + l]);
    }
}

__global__ void div_kernel(float4* __restrict__ out4, const int* __restrict__ counts) {
    const int i = blockIdx.x * 256 + threadIdx.x;   // 65536 float4s
    const int bl = i >> 5;                          // 32 float4 per (b,l)
    const float inv = 1.0f / fmaxf((float)counts[bl], 1.0f);
    float4 v = out4[i];
    v.x *= inv; v.y *= inv; v.z *= inv; v.w *= inv;
    out4[i] = v;
}

extern "C" void kernel_launch(void* const* d_in, const int* in_sizes, int n_in,
                              void* d_out, int out_size, void* d_ws, size_t ws_size,
                              hipStream_t stream) {
    const float* x      = (const float*)d_in[0];
    const int*   labels = (const int*)d_in[1];
    float* out  = (float*)d_out;
    int* counts = (int*)d_ws;   // 4*512 ints = 8 KB

    zero_kernel <<<(Bn * Ln * Cn / 4) / 256, 256, 0, stream>>>((float4*)out, counts);
    count_kernel<<<Bn * 16,                  256, 0, stream>>>(labels, counts);
    sum_kernel  <<<Bn * CG * SPLITS,         256, 0, stream>>>(x, labels, out);
    div_kernel  <<<(Bn * Ln * Cn / 4) / 256, 256, 0, stream>>>((float4*)out, counts);
}